// Round 4
// baseline (695.043 us; speedup 1.0000x reference)
//
#include <hip/hip_runtime.h>
#include <hip/hip_bf16.h>

// Problem constants
#define NN  20000
#define FF  256
#define HH  8
#define DD  64
#define HD  512      // H*D
#define MM  2
#define EE  320000
#define CC  5
#define HID 128

typedef __attribute__((ext_vector_type(8))) short short8;  // 8 x bf16 bits
typedef __attribute__((ext_vector_type(4))) float f32x4;

__device__ __forceinline__ float bf2f(__hip_bfloat16 v) { return __bfloat162float(v); }
__device__ __forceinline__ short f2bs(float v) {
  __hip_bfloat16 b = __float2bfloat16(v);
  return *reinterpret_cast<short*>(&b);
}
__device__ __forceinline__ int clampi(int v, int lo, int hi) {
  return v < lo ? lo : (v > hi ? hi : v);
}
// dual-dtype scalar input load: f32 ? float : bf16
__device__ __forceinline__ float ldin(const void* p, size_t i, bool f32) {
  return f32 ? ((const float*)p)[i] : bf2f(((const __hip_bfloat16*)p)[i]);
}

// ---------------- K0: dtype probe -----------------------------------------------------
// Read h's first 8192 uint16s as bf16 bit patterns. True bf16 N(0,1): exponent field
// concentrated near 127, ~0 outliers. fp32 data read as bf16: half the elements are
// random mantissa bits -> uniform exponents -> ~2500 outliers. Threshold 512.
__global__ void probe_k(const void* __restrict__ h, int* __restrict__ flag)
{
  __shared__ int sb[256];
  const unsigned short* ph = (const unsigned short*)h;
  int bad = 0;
  for (int i = threadIdx.x; i < 8192; i += 256) {
    int ex = (ph[i] >> 7) & 0xFF;
    if (ex < 64 || ex > 160) bad++;
  }
  sb[threadIdx.x] = bad;
  __syncthreads();
  for (int o = 128; o > 0; o >>= 1) {
    if ((int)threadIdx.x < o) sb[threadIdx.x] += sb[threadIdx.x + o];
    __syncthreads();
  }
  if (threadIdx.x == 0) flag[0] = (sb[0] > 512) ? 1 : 0;
}

// ---------------- K1: feat[m] = h @ W[m]  (bf16 out, fp32 accum via MFMA) --------------
__global__ __launch_bounds__(256) void gemm_feat_k(
    const void* __restrict__ h, const void* __restrict__ W,
    const int* __restrict__ flag, __hip_bfloat16* __restrict__ feat)
{
  const bool f32 = flag[0] != 0;
  const int m    = blockIdx.z;
  const int n0   = blockIdx.y * 64;
  const int row0 = blockIdx.x * 64;
  const int tid  = threadIdx.x;
  const int wave = tid >> 6, lane = tid & 63;
  const int l15  = lane & 15, quad = lane >> 4;
  __shared__ __align__(16) short As[64 * 32];
  __shared__ __align__(16) short Bs[32 * 64];
  f32x4 acc[4];
#pragma unroll
  for (int i = 0; i < 4; ++i) acc[i] = (f32x4){0.f, 0.f, 0.f, 0.f};

  for (int k0 = 0; k0 < FF; k0 += 32) {
    {  // stage A: 64 rows x 32 k, 8 elems/thread
      int r = tid >> 2, kg = tid & 3;
      size_t base = (size_t)(row0 + r) * FF + k0 + kg * 8;
      short sv[8];
      if (row0 + r < NN) {
        if (f32) {
          const float* hp = (const float*)h + base;
          float4 x = *(const float4*)hp, y = *(const float4*)(hp + 4);
          sv[0]=f2bs(x.x); sv[1]=f2bs(x.y); sv[2]=f2bs(x.z); sv[3]=f2bs(x.w);
          sv[4]=f2bs(y.x); sv[5]=f2bs(y.y); sv[6]=f2bs(y.z); sv[7]=f2bs(y.w);
        } else {
          uint4 u = *(const uint4*)((const __hip_bfloat16*)h + base);
          *(uint4*)sv = u;
        }
      } else {
#pragma unroll
        for (int j = 0; j < 8; ++j) sv[j] = 0;
      }
      *(uint4*)(&As[r * 32 + kg * 8]) = *(uint4*)sv;
    }
    {  // stage B: 32 k x 64 n
      int kb = tid >> 3, ng = tid & 7;
      size_t base = (size_t)m * FF * HD + (size_t)(k0 + kb) * HD + n0 + ng * 8;
      short sv[8];
      if (f32) {
        const float* wp = (const float*)W + base;
        float4 x = *(const float4*)wp, y = *(const float4*)(wp + 4);
        sv[0]=f2bs(x.x); sv[1]=f2bs(x.y); sv[2]=f2bs(x.z); sv[3]=f2bs(x.w);
        sv[4]=f2bs(y.x); sv[5]=f2bs(y.y); sv[6]=f2bs(y.z); sv[7]=f2bs(y.w);
      } else {
        uint4 u = *(const uint4*)((const __hip_bfloat16*)W + base);
        *(uint4*)sv = u;
      }
      *(uint4*)(&Bs[kb * 64 + ng * 8]) = *(uint4*)sv;
    }
    __syncthreads();
    // A frag: row = 16*wave + l15, k = quad*8 + j  (verified m120 A-layout)
    short8 a = *(const short8*)(&As[(16 * wave + l15) * 32 + quad * 8]);
#pragma unroll
    for (int nt = 0; nt < 4; ++nt) {
      short8 b;
#pragma unroll
      for (int j = 0; j < 8; ++j) b[j] = Bs[(quad * 8 + j) * 64 + nt * 16 + l15];
      acc[nt] = __builtin_amdgcn_mfma_f32_16x16x32_bf16(a, b, acc[nt], 0, 0, 0);
    }
    __syncthreads();
  }
  // C/D: col = lane&15, row = (lane>>4)*4 + reg  (verified m89)
#pragma unroll
  for (int nt = 0; nt < 4; ++nt)
#pragma unroll
    for (int r = 0; r < 4; ++r) {
      int row = row0 + 16 * wave + quad * 4 + r;
      if (row < NN)
        feat[(size_t)m * NN * HD + (size_t)row * HD + n0 + nt * 16 + l15] =
            __float2bfloat16(acc[nt][r]);
    }
}

// ---------------- K2: el/er projections ------------------------------------------------
__global__ void elr_k(const __hip_bfloat16* __restrict__ feat,
                      const void* __restrict__ al, const void* __restrict__ ar,
                      const int* __restrict__ flag,
                      float* __restrict__ el, float* __restrict__ er)
{
  const bool f32 = flag[0] != 0;
  int idx = blockIdx.x * blockDim.x + threadIdx.x;
  if (idx >= MM * NN * HH) return;
  int hh = idx & 7;
  int n  = (idx >> 3) % NN;
  int m  = idx / (NN * HH);
  const __hip_bfloat16* f = feat + ((size_t)m * NN + n) * HD + hh * 64;
  size_t pb = ((size_t)m * HH + hh) * 64;
  float sl = 0.f, sr = 0.f;
#pragma unroll 8
  for (int d = 0; d < 64; ++d) {
    float fv = bf2f(f[d]);
    sl += fv * ldin(al, pb + d, f32);
    sr += fv * ldin(ar, pb + d, f32);
  }
  el[idx] = sl;
  er[idx] = sr;
}

// ---------------- K3: CSR build (hist, chunked scan, scatter) -------------------------
__global__ void hist_k(const int* __restrict__ dst, int* __restrict__ counts)
{
  int e = blockIdx.x * blockDim.x + threadIdx.x;
  if (e >= MM * EE) return;
  int m = e / EE;
  int d = clampi(dst[e], 0, NN - 1);
  atomicAdd(&counts[m * NN + d], 1);
}

__global__ __launch_bounds__(256) void scan_k(const int* __restrict__ counts,
                                              int* __restrict__ offsets)
{
  const int m = blockIdx.x;
  const int CH = (NN + 255) / 256;  // 79
  const int lo = (int)threadIdx.x * CH;
  const int hi = min(NN, lo + CH);
  __shared__ int sdata[256];
  int s = 0;
  for (int i = lo; i < hi; ++i) s += counts[m * NN + i];
  sdata[threadIdx.x] = s;
  __syncthreads();
  if (threadIdx.x == 0) {
    int run = 0;
    for (int t = 0; t < 256; ++t) { int c = sdata[t]; sdata[t] = run; run += c; }
  }
  __syncthreads();
  int run = sdata[threadIdx.x];
  for (int i = lo; i < hi; ++i) {
    offsets[m * (NN + 1) + i] = run;
    run += counts[m * NN + i];
  }
  if (threadIdx.x == 255) offsets[m * (NN + 1) + NN] = run;  // == EE
}

__global__ void scatter_k(const int* __restrict__ dst, const int* __restrict__ offsets,
                          int* __restrict__ cursor, int* __restrict__ eidx)
{
  int e = blockIdx.x * blockDim.x + threadIdx.x;
  if (e >= MM * EE) return;
  int m = e / EE, ei = e % EE;
  int d = clampi(dst[e], 0, NN - 1);  // must match hist_k
  int pos = atomicAdd(&cursor[m * NN + d], 1);
  eidx[(size_t)m * EE + offsets[m * (NN + 1) + d] + pos] = ei;
}

// ---------------- K4: fused edge-softmax (exact) + aggregate + bias + elu -------------
__global__ __launch_bounds__(512) void aggregate_k(
    const int* __restrict__ src, const int* __restrict__ offsets,
    const int* __restrict__ eidx, const float* __restrict__ el,
    const float* __restrict__ er, const __hip_bfloat16* __restrict__ feat,
    const void* __restrict__ bias_g, const int* __restrict__ flag,
    __hip_bfloat16* __restrict__ z)
{
  const bool f32 = flag[0] != 0;
  const int n = blockIdx.x, m = blockIdx.y;
  const int tid = threadIdx.x;
  const int hh = tid >> 6, lane = tid & 63;
  __shared__ int   s_src[64];
  __shared__ float s_w[64 * 8];
  const int off = offsets[m * (NN + 1) + n];
  const int end = offsets[m * (NN + 1) + n + 1];
  const float er_h = er[((size_t)m * NN + n) * 8 + hh];

  // pass 1: per-head segment max
  float mh = -1e30f;
  for (int base = off; base < end; base += 64) {
    const int cnt = min(64, end - base);
    __syncthreads();
    if (tid < cnt) {
      int e = clampi(eidx[(size_t)m * EE + base + tid], 0, EE - 1);
      s_src[tid] = clampi(src[(size_t)m * EE + e], 0, NN - 1);
    }
    __syncthreads();
    if (lane < cnt) {
      float v = el[((size_t)m * NN + s_src[lane]) * 8 + hh] + er_h;
      v = v > 0.f ? v : 0.2f * v;
      mh = fmaxf(mh, v);
    }
  }
#pragma unroll
  for (int s = 32; s >= 1; s >>= 1) mh = fmaxf(mh, __shfl_xor(mh, s));

  // pass 2: exp(v - mh) weights, weighted gather-sum
  float acc = 0.f, den = 0.f;
  for (int base = off; base < end; base += 64) {
    const int cnt = min(64, end - base);
    __syncthreads();
    if (tid < cnt) {
      int e = clampi(eidx[(size_t)m * EE + base + tid], 0, EE - 1);
      s_src[tid] = clampi(src[(size_t)m * EE + e], 0, NN - 1);
    }
    __syncthreads();
    if (lane < cnt) {
      float v = el[((size_t)m * NN + s_src[lane]) * 8 + hh] + er_h;
      v = v > 0.f ? v : 0.2f * v;
      s_w[lane * 8 + hh] = __expf(fminf(v - mh, 0.f));  // <= 1 always
    }
    __syncthreads();
    for (int i = 0; i < cnt; ++i) {
      float w = s_w[i * 8 + hh];
      den += w;
      acc += w * bf2f(feat[((size_t)m * NN + s_src[i]) * HD + tid]);
    }
  }
  float o = acc / fmaxf(den, 1e-9f) + ldin(bias_g, (size_t)m * HD + tid, f32);
  float zv = o > 0.f ? o : expm1f(o);  // elu
  z[((size_t)m * NN + n) * HD + tid] = __float2bfloat16(zv);
}

// ---------------- K5: semantic GEMM + tanh + dot(W2) -> wlogit[M*N] -------------------
__global__ __launch_bounds__(256) void gemm_sem_k(
    const __hip_bfloat16* __restrict__ z, const void* __restrict__ W1,
    const void* __restrict__ b1, const void* __restrict__ W2,
    const int* __restrict__ flag, float* __restrict__ wlogit)
{
  const bool f32 = flag[0] != 0;
  const int n0   = blockIdx.y * 64;
  const int row0 = blockIdx.x * 64;
  const int tid  = threadIdx.x;
  const int wave = tid >> 6, lane = tid & 63;
  const int l15  = lane & 15, quad = lane >> 4;
  __shared__ __align__(16) short As[64 * 32];
  __shared__ __align__(16) short Bs[32 * 64];
  f32x4 acc[4];
#pragma unroll
  for (int i = 0; i < 4; ++i) acc[i] = (f32x4){0.f, 0.f, 0.f, 0.f};

  for (int k0 = 0; k0 < HD; k0 += 32) {
    {  // A: z rows (always bf16, ours)
      int r = tid >> 2, kg = tid & 3;
      *(uint4*)(&As[r * 32 + kg * 8]) =
          *(const uint4*)(z + (size_t)(row0 + r) * HD + k0 + kg * 8);
    }
    {  // B: W1 (dual dtype)
      int kb = tid >> 3, ng = tid & 7;
      size_t base = (size_t)(k0 + kb) * HID + n0 + ng * 8;
      short sv[8];
      if (f32) {
        const float* wp = (const float*)W1 + base;
        float4 x = *(const float4*)wp, y = *(const float4*)(wp + 4);
        sv[0]=f2bs(x.x); sv[1]=f2bs(x.y); sv[2]=f2bs(x.z); sv[3]=f2bs(x.w);
        sv[4]=f2bs(y.x); sv[5]=f2bs(y.y); sv[6]=f2bs(y.z); sv[7]=f2bs(y.w);
      } else {
        uint4 u = *(const uint4*)((const __hip_bfloat16*)W1 + base);
        *(uint4*)sv = u;
      }
      *(uint4*)(&Bs[kb * 64 + ng * 8]) = *(uint4*)sv;
    }
    __syncthreads();
    short8 a = *(const short8*)(&As[(16 * wave + l15) * 32 + quad * 8]);
#pragma unroll
    for (int nt = 0; nt < 4; ++nt) {
      short8 b;
#pragma unroll
      for (int j = 0; j < 8; ++j) b[j] = Bs[(quad * 8 + j) * 64 + nt * 16 + l15];
      acc[nt] = __builtin_amdgcn_mfma_f32_16x16x32_bf16(a, b, acc[nt], 0, 0, 0);
    }
    __syncthreads();
  }
  float b1v[4], w2v[4];
#pragma unroll
  for (int nt = 0; nt < 4; ++nt) {
    int col = n0 + nt * 16 + l15;
    b1v[nt] = ldin(b1, col, f32);
    w2v[nt] = ldin(W2, col, f32);
  }
#pragma unroll
  for (int r = 0; r < 4; ++r) {
    float val = 0.f;
#pragma unroll
    for (int nt = 0; nt < 4; ++nt) val += tanhf(acc[nt][r] + b1v[nt]) * w2v[nt];
#pragma unroll
    for (int s = 1; s < 16; s <<= 1) val += __shfl_xor(val, s);
    if (l15 == 0) atomicAdd(&wlogit[row0 + 16 * wave + quad * 4 + r], val);
  }
}

// ---------------- K6: reduce wlogit over nodes per metapath ---------------------------
__global__ void beta_reduce_k(const float* __restrict__ wlogit, float* __restrict__ wsum)
{
  int m = blockIdx.x;
  __shared__ float sd[256];
  float s = 0.f;
  for (int i = threadIdx.x; i < NN; i += blockDim.x) s += wlogit[m * NN + i];
  sd[threadIdx.x] = s;
  __syncthreads();
  for (int o = 128; o > 0; o >>= 1) {
    if ((int)threadIdx.x < o) sd[threadIdx.x] += sd[threadIdx.x + o];
    __syncthreads();
  }
  if (threadIdx.x == 0) wsum[m] = sd[0];
}

// ---------------- K7: beta softmax + weighted sum + classifier ------------------------
__global__ __launch_bounds__(256) void final_k(
    const __hip_bfloat16* __restrict__ z, const float* __restrict__ wsum,
    const void* __restrict__ predW, const void* __restrict__ predb,
    const int* __restrict__ flag, void* __restrict__ outv)
{
  const bool f32 = flag[0] != 0;
  const int wave = threadIdx.x >> 6, lane = threadIdx.x & 63;
  const int n = blockIdx.x * 4 + wave;
  if (n >= NN) return;
  float s0 = wsum[0] * (1.0f / NN), s1 = wsum[1] * (1.0f / NN);
  float mx = fmaxf(s0, s1);
  float e0 = __expf(s0 - mx), e1 = __expf(s1 - mx);
  float inv = 1.0f / (e0 + e1);
  float beta0 = e0 * inv, beta1 = e1 * inv;
  const __hip_bfloat16* z0 = z + (size_t)n * HD + lane * 8;
  const __hip_bfloat16* z1 = z + ((size_t)NN + n) * HD + lane * 8;
  float hv[8];
#pragma unroll
  for (int i = 0; i < 8; ++i) hv[i] = beta0 * bf2f(z0[i]) + beta1 * bf2f(z1[i]);
#pragma unroll
  for (int c = 0; c < CC; ++c) {
    float p = 0.f;
#pragma unroll
    for (int i = 0; i < 8; ++i) p += hv[i] * ldin(predW, (size_t)(lane * 8 + i) * CC + c, f32);
    for (int s = 1; s < 64; s <<= 1) p += __shfl_xor(p, s);
    if (lane == 0) {
      float res = p + ldin(predb, c, f32);
      if (f32) ((float*)outv)[n * CC + c] = res;
      else     ((__hip_bfloat16*)outv)[n * CC + c] = __float2bfloat16(res);
    }
  }
}

// ======================================================================================
extern "C" void kernel_launch(void* const* d_in, const int* in_sizes, int n_in,
                              void* d_out, int out_size, void* d_ws, size_t ws_size,
                              hipStream_t stream)
{
  const void* h      = d_in[0];
  const int*  src    = (const int*)d_in[1];
  const int*  dst    = (const int*)d_in[2];
  const void* W      = d_in[3];
  const void* al     = d_in[4];
  const void* ar     = d_in[5];
  const void* bias_g = d_in[6];
  const void* semW1  = d_in[7];
  const void* semb1  = d_in[8];
  const void* semW2  = d_in[9];
  const void* predW  = d_in[10];
  const void* predb  = d_in[11];

  // workspace carve (~88 MB): flag + small control buffers first, big tensors last
  char* p = (char*)d_ws;
  auto alloc = [&](size_t bytes) {
    char* r = p;
    p += (bytes + 255) & ~(size_t)255;
    return r;
  };
  int*   flag   = (int*)alloc(256);
  float* el     = (float*)alloc((size_t)MM * NN * HH * 4);
  float* er     = (float*)alloc((size_t)MM * NN * HH * 4);
  int*   counts = (int*)alloc((size_t)MM * NN * 4);
  int*   cursor = (int*)alloc((size_t)MM * NN * 4);
  int*   offs   = (int*)alloc((size_t)MM * (NN + 1) * 4);
  int*   eidx   = (int*)alloc((size_t)MM * EE * 4);
  float* wlogit = (float*)alloc((size_t)MM * NN * 4);
  float* wsum   = (float*)alloc(256);
  __hip_bfloat16* feat = (__hip_bfloat16*)alloc((size_t)MM * NN * HD * 2);
  __hip_bfloat16* z    = (__hip_bfloat16*)alloc((size_t)MM * NN * HD * 2);

  hipMemsetAsync(counts, 0, (size_t)MM * NN * 4, stream);
  hipMemsetAsync(cursor, 0, (size_t)MM * NN * 4, stream);
  hipMemsetAsync(wlogit, 0, (size_t)MM * NN * 4, stream);
  hipMemsetAsync(wsum, 0, 256, stream);

  probe_k<<<1, 256, 0, stream>>>(h, flag);
  gemm_feat_k<<<dim3((NN + 63) / 64, HD / 64, MM), 256, 0, stream>>>(h, W, flag, feat);
  elr_k<<<(MM * NN * HH + 255) / 256, 256, 0, stream>>>(feat, al, ar, flag, el, er);
  hist_k<<<(MM * EE + 255) / 256, 256, 0, stream>>>(dst, counts);
  scan_k<<<MM, 256, 0, stream>>>(counts, offs);
  scatter_k<<<(MM * EE + 255) / 256, 256, 0, stream>>>(dst, offs, cursor, eidx);
  aggregate_k<<<dim3(NN, MM), 512, 0, stream>>>(src, offs, eidx, el, er, feat, bias_g, flag, z);
  gemm_sem_k<<<dim3((MM * NN) / 64, HID / 64), 256, 0, stream>>>(z, semW1, semb1, semW2, flag, wlogit);
  beta_reduce_k<<<MM, 256, 0, stream>>>(wlogit, wsum);
  final_k<<<NN / 4, 256, 0, stream>>>(z, wsum, predW, predb, flag, d_out);
}

// Round 5
// 501.664 us; speedup vs baseline: 1.3855x; 1.3855x over previous
//
#include <hip/hip_runtime.h>
#include <hip/hip_bf16.h>

// Problem constants
#define NN  20000
#define FF  256
#define HH  8
#define DD  64
#define HD  512      // H*D
#define MM  2
#define EE  320000
#define CC  5
#define HID 128

typedef __attribute__((ext_vector_type(8))) short short8;  // 8 x bf16 bits
typedef __attribute__((ext_vector_type(4))) float f32x4;

__device__ __forceinline__ float bf2f(__hip_bfloat16 v) { return __bfloat162float(v); }
__device__ __forceinline__ short f2bs(float v) {
  __hip_bfloat16 b = __float2bfloat16(v);
  return *reinterpret_cast<short*>(&b);
}
__device__ __forceinline__ int clampi(int v, int lo, int hi) {
  return v < lo ? lo : (v > hi ? hi : v);
}
// dual-dtype scalar input load: f32 ? float : bf16
__device__ __forceinline__ float ldin(const void* p, size_t i, bool f32) {
  return f32 ? ((const float*)p)[i] : bf2f(((const __hip_bfloat16*)p)[i]);
}
// unpack 8 bf16 (in uint4) -> 8 f32
__device__ __forceinline__ void bf8_unpack(uint4 u, float f[8]) {
  f[0] = __uint_as_float(u.x << 16); f[1] = __uint_as_float(u.x & 0xffff0000u);
  f[2] = __uint_as_float(u.y << 16); f[3] = __uint_as_float(u.y & 0xffff0000u);
  f[4] = __uint_as_float(u.z << 16); f[5] = __uint_as_float(u.z & 0xffff0000u);
  f[6] = __uint_as_float(u.w << 16); f[7] = __uint_as_float(u.w & 0xffff0000u);
}

// ---------------- K0: dtype probe (bf16 vs fp32 inputs) -------------------------------
__global__ void probe_k(const void* __restrict__ h, int* __restrict__ flag)
{
  __shared__ int sb[256];
  const unsigned short* ph = (const unsigned short*)h;
  int bad = 0;
  for (int i = threadIdx.x; i < 8192; i += 256) {
    int ex = (ph[i] >> 7) & 0xFF;
    if (ex < 64 || ex > 160) bad++;
  }
  sb[threadIdx.x] = bad;
  __syncthreads();
  for (int o = 128; o > 0; o >>= 1) {
    if ((int)threadIdx.x < o) sb[threadIdx.x] += sb[threadIdx.x + o];
    __syncthreads();
  }
  if (threadIdx.x == 0) flag[0] = (sb[0] > 512) ? 1 : 0;
}

// ---------------- K1: feat[m] = h @ W[m] + fused el/er epilogue -----------------------
// grid (ceil(N/64), 8=heads, M), block 256. Tile 64x64 (64 cols == one head), BK=32.
__global__ __launch_bounds__(256) void gemm_feat_k(
    const void* __restrict__ h, const void* __restrict__ W,
    const void* __restrict__ al, const void* __restrict__ ar,
    const int* __restrict__ flag, __hip_bfloat16* __restrict__ feat,
    float* __restrict__ el, float* __restrict__ er)
{
  const bool f32 = flag[0] != 0;
  const int m    = blockIdx.z;
  const int hb   = blockIdx.y;        // head index == col-tile index
  const int n0   = hb * 64;
  const int row0 = blockIdx.x * 64;
  const int tid  = threadIdx.x;
  const int wave = tid >> 6, lane = tid & 63;
  const int l15  = lane & 15, quad = lane >> 4;
  __shared__ __align__(16) short As[64 * 32];
  __shared__ __align__(16) short Bs[32 * 64];
  f32x4 acc[4];
#pragma unroll
  for (int i = 0; i < 4; ++i) acc[i] = (f32x4){0.f, 0.f, 0.f, 0.f};

  for (int k0 = 0; k0 < FF; k0 += 32) {
    {  // stage A: 64 rows x 32 k, 8 elems/thread
      int r = tid >> 2, kg = tid & 3;
      size_t base = (size_t)(row0 + r) * FF + k0 + kg * 8;
      short sv[8];
      if (row0 + r < NN) {
        if (f32) {
          const float* hp = (const float*)h + base;
          float4 x = *(const float4*)hp, y = *(const float4*)(hp + 4);
          sv[0]=f2bs(x.x); sv[1]=f2bs(x.y); sv[2]=f2bs(x.z); sv[3]=f2bs(x.w);
          sv[4]=f2bs(y.x); sv[5]=f2bs(y.y); sv[6]=f2bs(y.z); sv[7]=f2bs(y.w);
        } else {
          *(uint4*)sv = *(const uint4*)((const __hip_bfloat16*)h + base);
        }
      } else {
#pragma unroll
        for (int j = 0; j < 8; ++j) sv[j] = 0;
      }
      *(uint4*)(&As[r * 32 + kg * 8]) = *(uint4*)sv;
    }
    {  // stage B: 32 k x 64 n
      int kb = tid >> 3, ng = tid & 7;
      size_t base = (size_t)m * FF * HD + (size_t)(k0 + kb) * HD + n0 + ng * 8;
      short sv[8];
      if (f32) {
        const float* wp = (const float*)W + base;
        float4 x = *(const float4*)wp, y = *(const float4*)(wp + 4);
        sv[0]=f2bs(x.x); sv[1]=f2bs(x.y); sv[2]=f2bs(x.z); sv[3]=f2bs(x.w);
        sv[4]=f2bs(y.x); sv[5]=f2bs(y.y); sv[6]=f2bs(y.z); sv[7]=f2bs(y.w);
      } else {
        *(uint4*)sv = *(const uint4*)((const __hip_bfloat16*)W + base);
      }
      *(uint4*)(&Bs[kb * 64 + ng * 8]) = *(uint4*)sv;
    }
    __syncthreads();
    // A frag: row = 16*wave + l15, k = quad*8 + j  (verified m120 A-layout)
    short8 a = *(const short8*)(&As[(16 * wave + l15) * 32 + quad * 8]);
#pragma unroll
    for (int nt = 0; nt < 4; ++nt) {
      short8 b;
#pragma unroll
      for (int j = 0; j < 8; ++j) b[j] = Bs[(quad * 8 + j) * 64 + nt * 16 + l15];
      acc[nt] = __builtin_amdgcn_mfma_f32_16x16x32_bf16(a, b, acc[nt], 0, 0, 0);
    }
    __syncthreads();
  }
  // epilogue 1: feat store. C/D: col = lane&15, row = (lane>>4)*4 + reg (verified m89)
#pragma unroll
  for (int nt = 0; nt < 4; ++nt)
#pragma unroll
    for (int r = 0; r < 4; ++r) {
      int row = row0 + 16 * wave + quad * 4 + r;
      if (row < NN)
        feat[(size_t)m * NN * HD + (size_t)row * HD + n0 + nt * 16 + l15] =
            __float2bfloat16(acc[nt][r]);
    }
  // epilogue 2: el/er — head dot-product over this block's 64 cols (fp32 acc)
  float al_v[4], ar_v[4];
#pragma unroll
  for (int nt = 0; nt < 4; ++nt) {
    size_t ai = (size_t)m * HH * DD + (size_t)hb * 64 + nt * 16 + l15;
    al_v[nt] = ldin(al, ai, f32);
    ar_v[nt] = ldin(ar, ai, f32);
  }
#pragma unroll
  for (int r = 0; r < 4; ++r) {
    int row = row0 + 16 * wave + quad * 4 + r;
    float sl = 0.f, sr = 0.f;
#pragma unroll
    for (int nt = 0; nt < 4; ++nt) {
      sl += acc[nt][r] * al_v[nt];
      sr += acc[nt][r] * ar_v[nt];
    }
#pragma unroll
    for (int s = 1; s < 16; s <<= 1) {
      sl += __shfl_xor(sl, s);
      sr += __shfl_xor(sr, s);
    }
    if (l15 == 0 && row < NN) {
      el[((size_t)m * NN + row) * 8 + hb] = sl;
      er[((size_t)m * NN + row) * 8 + hb] = sr;
    }
  }
}

// ---------------- K3: CSR build (hist, chunked scan, scatter) -------------------------
__global__ void hist_k(const int* __restrict__ dst, int* __restrict__ counts)
{
  int e = blockIdx.x * blockDim.x + threadIdx.x;
  if (e >= MM * EE) return;
  int m = e / EE;
  int d = clampi(dst[e], 0, NN - 1);
  atomicAdd(&counts[m * NN + d], 1);
}

__global__ __launch_bounds__(256) void scan_k(const int* __restrict__ counts,
                                              int* __restrict__ offsets)
{
  const int m = blockIdx.x;
  const int CH = (NN + 255) / 256;  // 79
  const int lo = (int)threadIdx.x * CH;
  const int hi = min(NN, lo + CH);
  __shared__ int sdata[256];
  int s = 0;
  for (int i = lo; i < hi; ++i) s += counts[m * NN + i];
  sdata[threadIdx.x] = s;
  __syncthreads();
  if (threadIdx.x == 0) {
    int run = 0;
    for (int t = 0; t < 256; ++t) { int c = sdata[t]; sdata[t] = run; run += c; }
  }
  __syncthreads();
  int run = sdata[threadIdx.x];
  for (int i = lo; i < hi; ++i) {
    offsets[m * (NN + 1) + i] = run;
    run += counts[m * NN + i];
  }
  if (threadIdx.x == 255) offsets[m * (NN + 1) + NN] = run;  // == EE
}

__global__ void scatter_k(const int* __restrict__ dst, const int* __restrict__ offsets,
                          int* __restrict__ cursor, int* __restrict__ eidx)
{
  int e = blockIdx.x * blockDim.x + threadIdx.x;
  if (e >= MM * EE) return;
  int m = e / EE, ei = e % EE;
  int d = clampi(dst[e], 0, NN - 1);  // must match hist_k
  int pos = atomicAdd(&cursor[m * NN + d], 1);
  eidx[(size_t)m * EE + offsets[m * (NN + 1) + d] + pos] = ei;
}

// ---------------- K4: fused edge-softmax + aggregate + bias + elu ---------------------
// One WAVE per node (block 512 = 8 nodes). Lane owns 8 d-slots (uint4 load/edge).
// Single pass: no max-subtraction (|e|<~7 -> exp safe in fp32, ratio identical).
__global__ __launch_bounds__(512) void aggregate_k(
    const int* __restrict__ src, const int* __restrict__ offsets,
    const int* __restrict__ eidx, const float* __restrict__ el,
    const float* __restrict__ er, const __hip_bfloat16* __restrict__ feat,
    const void* __restrict__ bias_g, const int* __restrict__ flag,
    __hip_bfloat16* __restrict__ z)
{
  const bool f32 = flag[0] != 0;
  const int m = blockIdx.y;
  const int wave = threadIdx.x >> 6, lane = threadIdx.x & 63;
  const int n = blockIdx.x * 8 + wave;
  if (n >= NN) return;
  const int hh = lane >> 3;  // head of this lane's 8 slots
  const int off = offsets[m * (NN + 1) + n];
  const int end = offsets[m * (NN + 1) + n + 1];
  const float er_h = er[((size_t)m * NN + n) * 8 + hh];
  const float* elm = el + (size_t)m * NN * 8;
  const int* eb = eidx + (size_t)m * EE;
  const int* sb = src + (size_t)m * EE;
  const __hip_bfloat16* fb = feat + (size_t)m * NN * HD + lane * 8;

  float acc[8];
#pragma unroll
  for (int j = 0; j < 8; ++j) acc[j] = 0.f;
  float den = 0.f;

  for (int base = off; base < end; base += 64) {
    const int cnt = min(64, end - base);
    int s_l = 0;
    if (lane < cnt) {
      int e = clampi(eb[base + lane], 0, EE - 1);
      s_l = clampi(sb[e], 0, NN - 1);
    }
    for (int i = 0; i < cnt; ++i) {
      int s = __shfl(s_l, i);
      float v = elm[s * 8 + hh] + er_h;
      v = v > 0.f ? v : 0.2f * v;      // leaky_relu 0.2
      float w = __expf(v);
      den += w;
      uint4 u = *(const uint4*)(fb + (size_t)s * HD);
      float f[8];
      bf8_unpack(u, f);
#pragma unroll
      for (int j = 0; j < 8; ++j) acc[j] += w * f[j];
    }
  }
  const float invden = 1.0f / fmaxf(den, 1e-9f);
  short sv[8];
#pragma unroll
  for (int j = 0; j < 8; ++j) {
    float o = acc[j] * invden + ldin(bias_g, (size_t)m * HD + lane * 8 + j, f32);
    o = o > 0.f ? o : expm1f(o);       // elu
    sv[j] = f2bs(o);
  }
  *(uint4*)(z + ((size_t)m * NN + n) * HD + lane * 8) = *(uint4*)sv;
}

// ---------------- K5: semantic GEMM + tanh + dot(W2) -> wlogit[M*N] -------------------
__global__ __launch_bounds__(256) void gemm_sem_k(
    const __hip_bfloat16* __restrict__ z, const void* __restrict__ W1,
    const void* __restrict__ b1, const void* __restrict__ W2,
    const int* __restrict__ flag, float* __restrict__ wlogit)
{
  const bool f32 = flag[0] != 0;
  const int n0   = blockIdx.y * 64;
  const int row0 = blockIdx.x * 64;
  const int tid  = threadIdx.x;
  const int wave = tid >> 6, lane = tid & 63;
  const int l15  = lane & 15, quad = lane >> 4;
  __shared__ __align__(16) short As[64 * 32];
  __shared__ __align__(16) short Bs[32 * 64];
  f32x4 acc[4];
#pragma unroll
  for (int i = 0; i < 4; ++i) acc[i] = (f32x4){0.f, 0.f, 0.f, 0.f};

  for (int k0 = 0; k0 < HD; k0 += 32) {
    {  // A: z rows (always bf16, internal)
      int r = tid >> 2, kg = tid & 3;
      *(uint4*)(&As[r * 32 + kg * 8]) =
          *(const uint4*)(z + (size_t)(row0 + r) * HD + k0 + kg * 8);
    }
    {  // B: W1 (dual dtype)
      int kb = tid >> 3, ng = tid & 7;
      size_t base = (size_t)(k0 + kb) * HID + n0 + ng * 8;
      short sv[8];
      if (f32) {
        const float* wp = (const float*)W1 + base;
        float4 x = *(const float4*)wp, y = *(const float4*)(wp + 4);
        sv[0]=f2bs(x.x); sv[1]=f2bs(x.y); sv[2]=f2bs(x.z); sv[3]=f2bs(x.w);
        sv[4]=f2bs(y.x); sv[5]=f2bs(y.y); sv[6]=f2bs(y.z); sv[7]=f2bs(y.w);
      } else {
        *(uint4*)sv = *(const uint4*)((const __hip_bfloat16*)W1 + base);
      }
      *(uint4*)(&Bs[kb * 64 + ng * 8]) = *(uint4*)sv;
    }
    __syncthreads();
    short8 a = *(const short8*)(&As[(16 * wave + l15) * 32 + quad * 8]);
#pragma unroll
    for (int nt = 0; nt < 4; ++nt) {
      short8 b;
#pragma unroll
      for (int j = 0; j < 8; ++j) b[j] = Bs[(quad * 8 + j) * 64 + nt * 16 + l15];
      acc[nt] = __builtin_amdgcn_mfma_f32_16x16x32_bf16(a, b, acc[nt], 0, 0, 0);
    }
    __syncthreads();
  }
  float b1v[4], w2v[4];
#pragma unroll
  for (int nt = 0; nt < 4; ++nt) {
    int col = n0 + nt * 16 + l15;
    b1v[nt] = ldin(b1, col, f32);
    w2v[nt] = ldin(W2, col, f32);
  }
#pragma unroll
  for (int r = 0; r < 4; ++r) {
    float val = 0.f;
#pragma unroll
    for (int nt = 0; nt < 4; ++nt) val += tanhf(acc[nt][r] + b1v[nt]) * w2v[nt];
#pragma unroll
    for (int s = 1; s < 16; s <<= 1) val += __shfl_xor(val, s);
    if (l15 == 0) atomicAdd(&wlogit[row0 + 16 * wave + quad * 4 + r], val);
  }
}

// ---------------- K6: reduce wlogit over nodes per metapath ---------------------------
__global__ void beta_reduce_k(const float* __restrict__ wlogit, float* __restrict__ wsum)
{
  int m = blockIdx.x;
  __shared__ float sd[256];
  float s = 0.f;
  for (int i = threadIdx.x; i < NN; i += blockDim.x) s += wlogit[m * NN + i];
  sd[threadIdx.x] = s;
  __syncthreads();
  for (int o = 128; o > 0; o >>= 1) {
    if ((int)threadIdx.x < o) sd[threadIdx.x] += sd[threadIdx.x + o];
    __syncthreads();
  }
  if (threadIdx.x == 0) wsum[m] = sd[0];
}

// ---------------- K7: beta softmax + weighted sum + classifier ------------------------
__global__ __launch_bounds__(256) void final_k(
    const __hip_bfloat16* __restrict__ z, const float* __restrict__ wsum,
    const void* __restrict__ predW, const void* __restrict__ predb,
    const int* __restrict__ flag, void* __restrict__ outv)
{
  const bool f32 = flag[0] != 0;
  const int wave = threadIdx.x >> 6, lane = threadIdx.x & 63;
  const int n = blockIdx.x * 4 + wave;
  if (n >= NN) return;
  float s0 = wsum[0] * (1.0f / NN), s1 = wsum[1] * (1.0f / NN);
  float mx = fmaxf(s0, s1);
  float e0 = __expf(s0 - mx), e1 = __expf(s1 - mx);
  float inv = 1.0f / (e0 + e1);
  float beta0 = e0 * inv, beta1 = e1 * inv;
  uint4 u0 = *(const uint4*)(z + (size_t)n * HD + lane * 8);
  uint4 u1 = *(const uint4*)(z + ((size_t)NN + n) * HD + lane * 8);
  float f0[8], f1[8], hv[8];
  bf8_unpack(u0, f0);
  bf8_unpack(u1, f1);
#pragma unroll
  for (int i = 0; i < 8; ++i) hv[i] = beta0 * f0[i] + beta1 * f1[i];
#pragma unroll
  for (int c = 0; c < CC; ++c) {
    float p = 0.f;
#pragma unroll
    for (int i = 0; i < 8; ++i) p += hv[i] * ldin(predW, (size_t)(lane * 8 + i) * CC + c, f32);
    for (int s = 1; s < 64; s <<= 1) p += __shfl_xor(p, s);
    if (lane == 0) {
      float res = p + ldin(predb, c, f32);
      if (f32) ((float*)outv)[n * CC + c] = res;
      else     ((__hip_bfloat16*)outv)[n * CC + c] = __float2bfloat16(res);
    }
  }
}

// ======================================================================================
extern "C" void kernel_launch(void* const* d_in, const int* in_sizes, int n_in,
                              void* d_out, int out_size, void* d_ws, size_t ws_size,
                              hipStream_t stream)
{
  const void* h      = d_in[0];
  const int*  src    = (const int*)d_in[1];
  const int*  dst    = (const int*)d_in[2];
  const void* W      = d_in[3];
  const void* al     = d_in[4];
  const void* ar     = d_in[5];
  const void* bias_g = d_in[6];
  const void* semW1  = d_in[7];
  const void* semb1  = d_in[8];
  const void* semW2  = d_in[9];
  const void* predW  = d_in[10];
  const void* predb  = d_in[11];

  // workspace carve: flag + small control buffers first, big tensors last
  char* p = (char*)d_ws;
  auto alloc = [&](size_t bytes) {
    char* r = p;
    p += (bytes + 255) & ~(size_t)255;
    return r;
  };
  int*   flag   = (int*)alloc(256);
  float* el     = (float*)alloc((size_t)MM * NN * HH * 4);
  float* er     = (float*)alloc((size_t)MM * NN * HH * 4);
  int*   counts = (int*)alloc((size_t)MM * NN * 4);
  int*   cursor = (int*)alloc((size_t)MM * NN * 4);
  int*   offs   = (int*)alloc((size_t)MM * (NN + 1) * 4);
  int*   eidx   = (int*)alloc((size_t)MM * EE * 4);
  float* wlogit = (float*)alloc((size_t)MM * NN * 4);
  float* wsum   = (float*)alloc(256);
  __hip_bfloat16* feat = (__hip_bfloat16*)alloc((size_t)MM * NN * HD * 2);
  __hip_bfloat16* z    = (__hip_bfloat16*)alloc((size_t)MM * NN * HD * 2);

  hipMemsetAsync(counts, 0, (size_t)MM * NN * 4, stream);
  hipMemsetAsync(cursor, 0, (size_t)MM * NN * 4, stream);
  hipMemsetAsync(wlogit, 0, (size_t)MM * NN * 4, stream);

  probe_k<<<1, 256, 0, stream>>>(h, flag);
  gemm_feat_k<<<dim3((NN + 63) / 64, HH, MM), 256, 0, stream>>>(h, W, al, ar, flag, feat, el, er);
  hist_k<<<(MM * EE + 255) / 256, 256, 0, stream>>>(dst, counts);
  scan_k<<<MM, 256, 0, stream>>>(counts, offs);
  scatter_k<<<(MM * EE + 255) / 256, 256, 0, stream>>>(dst, offs, cursor, eidx);
  aggregate_k<<<dim3((NN + 7) / 8, MM), 512, 0, stream>>>(src, offs, eidx, el, er, feat, bias_g, flag, z);
  gemm_sem_k<<<dim3((MM * NN) / 64, HID / 64), 256, 0, stream>>>(z, semW1, semb1, semW2, flag, wlogit);
  beta_reduce_k<<<MM, 256, 0, stream>>>(wlogit, wsum);
  final_k<<<NN / 4, 256, 0, stream>>>(z, wsum, predW, predb, flag, d_out);
}